// Round 4
// baseline (94.454 us; speedup 1.0000x reference)
//
#include <hip/hip_runtime.h>

// Problem constants (from reference)
#define B        8192
#define N_IN     8
#define N_MFS    4
#define N_RULES  2048

#define THREADS  512
#define NB       16                   // batches per block
#define RPT      4                    // rules per thread: THREADS*RPT == N_RULES
#define LUT_W    101                  // words per batch pair-LUT (100 used + 1 pad)
#define XS_W     (N_IN * N_MFS)       // 32 floats per batch

// R10 == R9 resubmitted verbatim: R9's bench died on container acquisition
// ("MI355X container failed twice"), not on the kernel (no compile error,
// no pass/fail verdict). Source audited: all bounds legal, no device sync,
// 8.4KB LDS, grid 512x512thr. Keeping the A/B intact:
//
// R9: RSPLIT 8 -> 1. One block covers ALL 2048 rules for its 16 batches.
//  Post-mortem R7/R8: occupancy (2->8 blk/CU) null, NT->regular null.
//  Three structurally different kernels all sat at kernel ~= 36-39us
//  (dur_us minus the ~45us harness poison fill). Shared property left
//  unvaried: every version wrote 1KB column chunks per block, with each
//  output row assembled from 8 blocks on different XCDs; the 6 TB/s
//  harness fill writes long contiguous ranges per workgroup.
//  This version:
//  - Each bl-step stores ONE ENTIRE 8KB row contiguously (wave=1KB,
//    block=8KB): maximally fill-like write stream.
//  - LUT-build redundancy / mf re-decode drops 8x (RSPLIT gone).
//  - 512 blocks = 2 blocks/CU = 64/XCD (even); LDS 8.4KB/block.
//  - Main loop: 16 broadcast ds_read_b32 (imm batch offsets) + 12 muls
//    + 1 regular float4 store per batch. 25-word-window gather ->
//    same-bank implies same-word -> conflict-free (verified counter 0).
__global__ __launch_bounds__(THREADS) void fire_kernel(
        const float* __restrict__ x,
        const int*   __restrict__ mf,
        float* __restrict__ out)
{
    __shared__ float xs[NB * XS_W];      // 2 KB: 16 batches x 32 floats
    __shared__ float slut[NB * LUT_W];   // 6.3 KB: 16 batches x 101 words

    const int tid = threadIdx.x;
    const int b0  = blockIdx.x * NB;

    // ---- Stage this block's x slice: 512 floats = 128 x float4, coalesced.
    if (tid < (NB * XS_W) / 4) {
        ((float4*)xs)[tid] = ((const float4*)(x + (size_t)b0 * XS_W))[tid];
    }

    // ---- Pack this thread's 4 consecutive rules into 16 word offsets.
    int woff[RPT][4];
#pragma unroll
    for (int j = 0; j < RPT; ++j) {
        const int r = tid * RPT + j;
        const int4* mr = (const int4*)(mf + (size_t)r * N_IN);
        const int4 lo = mr[0];
        const int4 hi = mr[1];
        const int idx[8] = {lo.x, lo.y, lo.z, lo.w, hi.x, hi.y, hi.z, hi.w};
#pragma unroll
        for (int p = 0; p < 4; ++p) {
            const int a = idx[2*p]   < 0 ? 4 : idx[2*p];
            const int b = idx[2*p+1] < 0 ? 4 : idx[2*p+1];
            woff[j][p] = p * 25 + a * 5 + b;
        }
    }
    __syncthreads();   // xs ready

    // ---- Build pair-product LUTs from LDS-resident x (1600 entries,
    //      512 threads -> ~3 iters): slut[bl*101 + p*25+a*5+b] = va*vb.
    for (int e = tid; e < NB * 100; e += THREADS) {
        const int bl   = e / 100;
        const int rest = e - bl * 100;
        const int p    = rest / 25;
        const int c    = rest - p * 25;
        const int a    = c / 5;
        const int bb   = c - a * 5;
        const float* xb = xs + bl * XS_W;
        const float va = (a  < 4) ? xb[(2*p)   * N_MFS + a ] : 1.0f;
        const float vb = (bb < 4) ? xb[(2*p+1) * N_MFS + bb] : 1.0f;
        slut[bl * LUT_W + rest] = va * vb;
    }
    __syncthreads();   // slut ready

    // ---- Main loop: per batch, 16 ds_read_b32 + 12 muls + one float4
    //      store; block writes the full contiguous 8KB row.
#pragma unroll 2
    for (int bl = 0; bl < NB; ++bl) {
        const float* lb = slut + bl * LUT_W;
        float r0, r1, r2, r3;
        {
            const float v0 = lb[woff[0][0]], v1 = lb[woff[0][1]];
            const float v2 = lb[woff[0][2]], v3 = lb[woff[0][3]];
            r0 = (v0 * v1) * (v2 * v3);
        }
        {
            const float v0 = lb[woff[1][0]], v1 = lb[woff[1][1]];
            const float v2 = lb[woff[1][2]], v3 = lb[woff[1][3]];
            r1 = (v0 * v1) * (v2 * v3);
        }
        {
            const float v0 = lb[woff[2][0]], v1 = lb[woff[2][1]];
            const float v2 = lb[woff[2][2]], v3 = lb[woff[2][3]];
            r2 = (v0 * v1) * (v2 * v3);
        }
        {
            const float v0 = lb[woff[3][0]], v1 = lb[woff[3][1]];
            const float v2 = lb[woff[3][2]], v3 = lb[woff[3][3]];
            r3 = (v0 * v1) * (v2 * v3);
        }
        *(float4*)(out + (size_t)(b0 + bl) * N_RULES + tid * RPT) =
            make_float4(r0, r1, r2, r3);
    }
}

extern "C" void kernel_launch(void* const* d_in, const int* in_sizes, int n_in,
                              void* d_out, int out_size, void* d_ws, size_t ws_size,
                              hipStream_t stream) {
    const float* x  = (const float*)d_in[0];   // (B, N_IN, N_MFS) fp32
    const int*   mf = (const int*)d_in[1];     // (N_RULES, N_IN) int32
    float* out = (float*)d_out;                // (B, N_RULES) fp32
    (void)d_ws; (void)ws_size;

    fire_kernel<<<B / NB, THREADS, 0, stream>>>(x, mf, out);
}

// Round 5
// 79.853 us; speedup vs baseline: 1.1829x; 1.1829x over previous
//
#include <hip/hip_runtime.h>

// Problem constants (from reference)
#define B        8192
#define N_IN     8
#define N_MFS    4
#define N_RULES  2048

#define THREADS  256
#define NB       16                   // batches per block
#define RSPLIT   4                    // rule groups: grid = (B/NB)*RSPLIT = 2048 blocks
#define RPB      (N_RULES / RSPLIT)   // 512 rules/block -> 2 rules/thread
#define LUT_W    101                  // words per batch pair-LUT (100 used + 1 pad)
#define XS_W     (N_IN * N_MFS)       // 32 floats per batch

typedef float vfloat2 __attribute__((ext_vector_type(2)));

// R11: keep R7's proven optimum on every measured axis, trim instr count.
//  Cross-round evidence (R6/R7/R8/R10): NT > regular stores (-2.9us @4B,
//  -10us @16B: NT's L2 no-allocate helps this never-re-read stream);
//  32 waves/CU best; full-row vs column-chunk write pattern is a null
//  (R6 full-row lost to R7 chunks). R7 config retained: NT stores,
//  2048 blocks = 8/CU = 32 waves/CU, column-chunk writes, conflict-free
//  25-word-window LDS gather (counter-verified 0).
//  Changes vs R7 (all pure instruction-count cuts on the same pipes):
//  - 2 rules/thread: store instrs halved (one 8B NT float2 per batch,
//    wave chunk 256B -> 512B contiguous).
//  - RSPLIT 8 -> 4: per-batch LUT build redundancy halved (6.6M -> 3.3M
//    entries device-wide); ds_read count invariant (4/output).
//  - NB 32 -> 16 keeps grid at 2048.
__global__ __launch_bounds__(THREADS) void fire_kernel(
        const float* __restrict__ x,
        const int*   __restrict__ mf,
        float* __restrict__ out)
{
    __shared__ float xs[NB * XS_W];      // 2 KB: 16 batches x 32 floats
    __shared__ float slut[NB * LUT_W];   // 6.4 KB: 16 batches x 101 words

    const int tid = threadIdx.x;
    const int rg  = blockIdx.x;          // rule group 0..3
    const int bg  = blockIdx.y;          // batch group 0..511
    const int b0  = bg * NB;
    const int r0  = rg * RPB + tid * 2;  // this thread's 2 consecutive rules

    // ---- Stage this block's x slice: 512 floats = 128 x float4, coalesced.
    if (tid < (NB * XS_W) / 4) {
        ((float4*)xs)[tid] = ((const float4*)(x + (size_t)b0 * XS_W))[tid];
    }

    // ---- Pack this thread's 2 rules into 8 register word offsets.
    int woff[2][4];
#pragma unroll
    for (int j = 0; j < 2; ++j) {
        const int4* mr = (const int4*)(mf + (size_t)(r0 + j) * N_IN);
        const int4 lo = mr[0];
        const int4 hi = mr[1];
        const int idx[8] = {lo.x, lo.y, lo.z, lo.w, hi.x, hi.y, hi.z, hi.w};
#pragma unroll
        for (int p = 0; p < 4; ++p) {
            const int a = idx[2*p]   < 0 ? 4 : idx[2*p];
            const int b = idx[2*p+1] < 0 ? 4 : idx[2*p+1];
            woff[j][p] = p * 25 + a * 5 + b;
        }
    }
    __syncthreads();   // xs ready

    // ---- Build pair-product LUTs from LDS-resident x (1600 entries,
    //      256 threads -> ~6 iters): slut[bl*101 + p*25+a*5+b] = va*vb.
    for (int e = tid; e < NB * 100; e += THREADS) {
        const int bl   = e / 100;
        const int rest = e - bl * 100;
        const int p    = rest / 25;
        const int c    = rest - p * 25;
        const int a    = c / 5;
        const int bb   = c - a * 5;
        const float* xb = xs + bl * XS_W;
        const float va = (a  < 4) ? xb[(2*p)   * N_MFS + a ] : 1.0f;
        const float vb = (bb < 4) ? xb[(2*p+1) * N_MFS + bb] : 1.0f;
        slut[bl * LUT_W + rest] = va * vb;
    }
    __syncthreads();   // slut ready

    // ---- Main loop: per batch, 8 broadcast ds_read_b32 (imm batch
    //      offsets) + 6 muls + one 8B NT store (wave = 512B contiguous).
    float* o = out + (size_t)b0 * N_RULES + rg * RPB + tid * 2;
#pragma unroll 4
    for (int bl = 0; bl < NB; ++bl) {
        const float* lb = slut + bl * LUT_W;
        vfloat2 res;
        {
            const float v0 = lb[woff[0][0]], v1 = lb[woff[0][1]];
            const float v2 = lb[woff[0][2]], v3 = lb[woff[0][3]];
            res.x = (v0 * v1) * (v2 * v3);
        }
        {
            const float v0 = lb[woff[1][0]], v1 = lb[woff[1][1]];
            const float v2 = lb[woff[1][2]], v3 = lb[woff[1][3]];
            res.y = (v0 * v1) * (v2 * v3);
        }
        __builtin_nontemporal_store(res, (vfloat2*)(o + (size_t)bl * N_RULES));
    }
}

extern "C" void kernel_launch(void* const* d_in, const int* in_sizes, int n_in,
                              void* d_out, int out_size, void* d_ws, size_t ws_size,
                              hipStream_t stream) {
    const float* x  = (const float*)d_in[0];   // (B, N_IN, N_MFS) fp32
    const int*   mf = (const int*)d_in[1];     // (N_RULES, N_IN) int32
    float* out = (float*)d_out;                // (B, N_RULES) fp32
    (void)d_ws; (void)ws_size;

    dim3 grid(RSPLIT, B / NB);
    fire_kernel<<<grid, THREADS, 0, stream>>>(x, mf, out);
}